// Round 10
// baseline (179.022 us; speedup 1.0000x reference)
//
#include <hip/hip_runtime.h>
#include <hip/hip_bf16.h>

#define NEG_SLOPE_C 0.1f
#define LOG2E_C 1.4426950408889634f
#define NEGB_C (-1.3e16f)            // -9e15 * log2(e), rounded down (log2-domain mask value)

constexpr int B_ = 2, N_ = 4096, IN_ = 64, H_ = 4, D_ = 32;

typedef float f32x16 __attribute__((ext_vector_type(16)));
typedef __bf16 bf16x8 __attribute__((ext_vector_type(8)));

__device__ inline unsigned short f2bfu(float x) {           // RNE f32 -> bf16 bits
    unsigned u = __float_as_uint(x);
    return (unsigned short)((u + 0x7fffu + ((u >> 16) & 1u)) >> 16);
}
__device__ inline float bfu2f(unsigned short s) { return __uint_as_float(((unsigned)s) << 16); }
__device__ inline bf16x8 ld_bf8(const unsigned short* p) {
    uint4 r = *reinterpret_cast<const uint4*>(p);
    return __builtin_bit_cast(bf16x8, r);
}

// -------- Kernel P: transpose fc_w [128][64] -> fc_wT [64][128] (32 KB, trivial) --------
__global__ __launch_bounds__(256) void prep_fcT(const float* __restrict__ fc_w,
                                                float* __restrict__ fc_wT) {
    int t = blockIdx.x * 256 + threadIdx.x;   // 8192 threads
    int c = t >> 6, k = t & 63;
    fc_wT[k * 128 + c] = fc_w[c * 64 + k];
}

// ---------- Kernel A (r1-proven): adj -> maskb[q*(N/32) + kchunk], bit j = adj[q][kchunk*32+j] ----------
__global__ __launch_bounds__(256) void pack_adj(const float* __restrict__ adj,
                                                unsigned* __restrict__ maskbits) {
    long long idx = (long long)blockIdx.x * blockDim.x + threadIdx.x;
    float a = adj[idx];
    unsigned long long ball = __ballot(a != 0.0f);
    int lane = threadIdx.x & 63;
    if (lane == 0)       maskbits[idx >> 5] = (unsigned)(ball & 0xffffffffULL);
    else if (lane == 32) maskbits[idx >> 5] = (unsigned)(ball >> 32);
}

// ------------- Kernel B: projections -> bf16 hi/lo splits + V row-major (bf16) -------------
__global__ __launch_bounds__(128) void proj_kernel(
    const float* __restrict__ x, const float* __restrict__ fc_wT,
    const float* __restrict__ fc_b, const float* __restrict__ Q1,
    const float* __restrict__ Q2, const float* __restrict__ K,
    const float* __restrict__ V,
    unsigned short* __restrict__ QtH, unsigned short* __restrict__ QtL,
    unsigned short* __restrict__ KtH, unsigned short* __restrict__ KtL,
    unsigned short* __restrict__ Vt) {
    const int t = threadIdx.x;          // 0..127
    const int h = t >> 5, e = t & 31;
    const float* q1p = Q1 + h * D_ * D_;
    const float* q2p = Q2 + h * D_ * D_;
    const float* kp  = K  + h * D_ * D_;
    const float* vp  = V  + h * D_ * D_;
    __shared__ float xr[IN_];
    __shared__ float xp[H_ * D_];
    const float bias = fc_b[t];
    for (int rr = 0; rr < 8; ++rr) {
        const int bn = blockIdx.x * 8 + rr;   // 0..B*N-1
        const int b = bn / N_, n = bn % N_;
        if (t < IN_) xr[t] = x[(long long)bn * IN_ + t];
        __syncthreads();
        float acc = bias;
        #pragma unroll
        for (int k = 0; k < IN_; ++k) acc += xr[k] * fc_wT[k * 128 + t];  // coalesced, L1-hit
        xp[t] = acc;
        __syncthreads();
        const float* xph = xp + h * D_;
        float a1 = 0.f, a2 = 0.f, ak = 0.f, av = 0.f;
        #pragma unroll
        for (int d = 0; d < D_; ++d) {
            float xv = xph[d];
            a1 += xv * q1p[d * D_ + e];
            a2 += xv * q2p[d * D_ + e];
            ak += xv * kp [d * D_ + e];
            av += xv * vp [d * D_ + e];
        }
        float q = a1 + a2;
        q = q >= 0.f ? q : NEG_SLOPE_C * q;   // Qt = leaky(Qt1+Qt2)
        size_t o = ((size_t)(b * H_ + h) * N_ + n) * D_ + e;
        unsigned short qh = f2bfu(q);
        QtH[o] = qh;
        QtL[o] = f2bfu(q - bfu2f(qh));
        unsigned short kh = f2bfu(ak);
        KtH[o] = kh;
        KtL[o] = f2bfu(ak - bfu2f(kh));
        Vt[o]  = f2bfu(av);                   // row-major, coalesced
        __syncthreads();
    }
}

// ------------- Kernel B2: Vt [bh][n][d] -> VtT [bh][d][n] (LDS tile transpose) -------------
__global__ __launch_bounds__(256) void vtrans(const unsigned short* __restrict__ Vt,
                                              unsigned short* __restrict__ VtT) {
    const int bh = blockIdx.x >> 6;
    const int n0 = (blockIdx.x & 63) * 64;
    __shared__ unsigned short tile[64][34];
    const int t = threadIdx.x;
    {
        const int r = t >> 2, c = (t & 3) * 8;
        uint4 v = *reinterpret_cast<const uint4*>(Vt + ((size_t)bh * N_ + n0 + r) * D_ + c);
        *reinterpret_cast<uint4*>(&tile[r][c]) = v;
    }
    __syncthreads();
    {
        const int d = t >> 3, nc = (t & 7) * 8;
        unsigned short tmp[8];
        #pragma unroll
        for (int j = 0; j < 8; ++j) tmp[j] = tile[nc + j][d];
        *reinterpret_cast<uint4*>(VtT + ((size_t)bh * D_ + d) * N_ + n0 + nc) =
            *reinterpret_cast<uint4*>(tmp);
    }
}

// ---------------- Kernel C: MFMA flash attention PARTIAL (2 blocks per query-group) ----------------
// grid 2048: (bh, qg, half). 4 waves/block, each wave = 512-key strip; block LDS-merges its
// 4 strips and writes un-normalized partial (O, m, l) to ws. 256 thr, 17.9 KB LDS, VGPR~32
// -> 8 blocks/CU (32 waves) resident.
__global__ __launch_bounds__(256, 8) void flash_part(
    const unsigned short* __restrict__ QtH, const unsigned short* __restrict__ QtL,
    const unsigned short* __restrict__ KtH, const unsigned short* __restrict__ KtL,
    const unsigned short* __restrict__ VtT, const unsigned* __restrict__ maskb,
    float* __restrict__ partO, float* __restrict__ partM, float* __restrict__ partL) {
    const int bid = blockIdx.x;      // 2048 blocks
    const int bh = bid >> 8;         // 0..7
    const int qg = (bid >> 1) & 127; // 32-query group
    const int half = bid & 1;        // key half: 0 -> keys 0..2047, 1 -> 2048..4095
    const int t = threadIdx.x;
    const int w = t >> 6;            // wave 0..3
    const int wu = __builtin_amdgcn_readfirstlane(w);
    const int l = t & 63;
    const int lq = l & 31;           // this lane's query column
    const int hi = l >> 5;
    const int q0 = qg * 32;
    const int strip = half * 4 + wu; // 0..7, this wave's 512-key strip

    const size_t bhND = (size_t)bh * N_ * D_;
    // Q B-fragments: B[k=dim][col=q]
    const unsigned short* qbh = QtH + bhND + (size_t)(q0 + lq) * D_ + hi * 8;
    const unsigned short* qbl = QtL + bhND + (size_t)(q0 + lq) * D_ + hi * 8;
    const bf16x8 qh0 = ld_bf8(qbh), qh1 = ld_bf8(qbh + 16);
    const bf16x8 ql0 = ld_bf8(qbl), ql1 = ld_bf8(qbl + 16);

    f32x16 acc = {};                 // O^T: row=d, col=q
    float m_run = -3.0e38f, l_run = 0.f;   // m in log2 units
    const float negb = NEGB_C;
    const float C1 = 0.55f * LOG2E_C, C2 = 0.45f * LOG2E_C;

    const int kw0 = strip * 512;     // this wave's 512-key strip
    const unsigned short* kh_p = KtH + bhND + (size_t)(kw0 + lq) * D_ + hi * 8;
    const unsigned short* kl_p = KtL + bhND + (size_t)(kw0 + lq) * D_ + hi * 8;
    const unsigned short* v_p  = VtT + ((size_t)bh * D_ + lq) * N_ + kw0 + hi * 8;
    // per-lane mask row: this query's key-chunk words (L1-resident, reused across tt)
    const unsigned* mrow = maskb + (size_t)(q0 + lq) * (N_ / 32) + strip * 16;

    for (int tt = 0; tt < 16; ++tt) {
        const unsigned word = mrow[tt];              // 32 key-bits for this lane's query
        const unsigned word_h = word >> (hi * 4);    // pre-shift for this half-wave's row offset
        const bf16x8 kh0v = ld_bf8(kh_p), kh1v = ld_bf8(kh_p + 16);
        const bf16x8 kl0v = ld_bf8(kl_p), kl1v = ld_bf8(kl_p + 16);
        const bf16x8 v0   = ld_bf8(v_p),  v1   = ld_bf8(v_p + 16);
        kh_p += 32 * D_; kl_p += 32 * D_; v_p += 32;

        f32x16 s = {};
        s = __builtin_amdgcn_mfma_f32_32x32x16_bf16(kh0v, qh0, s, 0, 0, 0);
        s = __builtin_amdgcn_mfma_f32_32x32x16_bf16(kh1v, qh1, s, 0, 0, 0);
        s = __builtin_amdgcn_mfma_f32_32x32x16_bf16(kh0v, ql0, s, 0, 0, 0);
        s = __builtin_amdgcn_mfma_f32_32x32x16_bf16(kh1v, ql1, s, 0, 0, 0);
        s = __builtin_amdgcn_mfma_f32_32x32x16_bf16(kl0v, qh0, s, 0, 0, 0);
        s = __builtin_amdgcn_mfma_f32_32x32x16_bf16(kl1v, qh1, s, 0, 0, 0);

        // am = log2-scaled leaky score, masked via per-lane bit test
        float am[16];
        #pragma unroll
        for (int r = 0; r < 16; ++r) {
            const int sh = (r & 3) + 8 * (r >> 2);   // key row within half-wave, compile-time
            const float v = s[r];
            const float a = fmaf(C2, fabsf(v), C1 * v);
            am[r] = ((word_h >> sh) & 1u) ? a : negb;
        }
        // row max, cross-half via shfl_xor (r5-proven path)
        const float x0 = fmaxf(fmaxf(am[0], am[1]), am[2]);
        const float x1 = fmaxf(fmaxf(am[3], am[4]), am[5]);
        const float x2 = fmaxf(fmaxf(am[6], am[7]), am[8]);
        const float x3 = fmaxf(fmaxf(am[9], am[10]), am[11]);
        const float x4 = fmaxf(fmaxf(am[12], am[13]), am[14]);
        const float y0 = fmaxf(fmaxf(x0, x1), x2);
        const float y1 = fmaxf(fmaxf(x3, x4), am[15]);
        float cmax = fmaxf(y0, y1);
        cmax = fmaxf(cmax, __shfl_xor(cmax, 32));
        if (!__all(cmax <= m_run)) {
            const float nm = fmaxf(m_run, cmax);
            const float sc = __builtin_amdgcn_exp2f(m_run - nm);
            l_run *= sc;
            #pragma unroll
            for (int r = 0; r < 16; ++r) acc[r] *= sc;
            m_run = nm;
        }
        float e[16];
        #pragma unroll
        for (int r = 0; r < 16; ++r) e[r] = __builtin_amdgcn_exp2f(am[r] - m_run);
        const float s0 = (e[0] + e[1]) + (e[2] + e[3]);
        const float s1 = (e[4] + e[5]) + (e[6] + e[7]);
        const float s2 = (e[8] + e[9]) + (e[10] + e[11]);
        const float s3 = (e[12] + e[13]) + (e[14] + e[15]);
        float lsum = (s0 + s1) + (s2 + s3);
        lsum += __shfl_xor(lsum, 32);
        l_run += lsum;
        // P -> bf16 pairs: 8 cvt_pk + 4 permlane32_swap (distinct operands -> safe; proven)
        unsigned c0w, c1w, c2w, c3w, c4w, c5w, c6w, c7w;
        asm("v_cvt_pk_bf16_f32 %0, %1, %2" : "=v"(c0w) : "v"(e[0]),  "v"(e[1]));
        asm("v_cvt_pk_bf16_f32 %0, %1, %2" : "=v"(c1w) : "v"(e[2]),  "v"(e[3]));
        asm("v_cvt_pk_bf16_f32 %0, %1, %2" : "=v"(c2w) : "v"(e[4]),  "v"(e[5]));
        asm("v_cvt_pk_bf16_f32 %0, %1, %2" : "=v"(c3w) : "v"(e[6]),  "v"(e[7]));
        asm("v_cvt_pk_bf16_f32 %0, %1, %2" : "=v"(c4w) : "v"(e[8]),  "v"(e[9]));
        asm("v_cvt_pk_bf16_f32 %0, %1, %2" : "=v"(c5w) : "v"(e[10]), "v"(e[11]));
        asm("v_cvt_pk_bf16_f32 %0, %1, %2" : "=v"(c6w) : "v"(e[12]), "v"(e[13]));
        asm("v_cvt_pk_bf16_f32 %0, %1, %2" : "=v"(c7w) : "v"(e[14]), "v"(e[15]));
        asm("v_permlane32_swap_b32 %0, %1" : "+v"(c0w), "+v"(c2w));
        asm("v_permlane32_swap_b32 %0, %1" : "+v"(c1w), "+v"(c3w));
        asm("v_permlane32_swap_b32 %0, %1" : "+v"(c4w), "+v"(c6w));
        asm("v_permlane32_swap_b32 %0, %1" : "+v"(c5w), "+v"(c7w));
        const uint4 b0u = make_uint4(c0w, c1w, c2w, c3w);
        const uint4 b1u = make_uint4(c4w, c5w, c6w, c7w);
        acc = __builtin_amdgcn_mfma_f32_32x32x16_bf16(v0, __builtin_bit_cast(bf16x8, b0u), acc, 0, 0, 0);
        acc = __builtin_amdgcn_mfma_f32_32x32x16_bf16(v1, __builtin_bit_cast(bf16x8, b1u), acc, 0, 0, 0);
    }

    // ---- cross-wave flash merge (4 strip partials) -> un-normalized block partial ----
    __shared__ float o_lds[4][32][33];
    __shared__ float m_l[4][32];
    __shared__ float l_l[4][32];
    if (hi == 0) { m_l[w][lq] = m_run; l_l[w][lq] = l_run; }
    #pragma unroll
    for (int r = 0; r < 16; ++r) {
        const int d = (r & 3) + 8 * (r >> 2) + 4 * hi;
        o_lds[w][d][lq] = acc[r];
    }
    __syncthreads();
    {
        const int q = t >> 3;        // 0..31
        const int d2 = t & 7;        // d = d2*4 .. d2*4+3 (consecutive lanes -> consecutive 16B)
        const float M = fmaxf(fmaxf(m_l[0][q], m_l[1][q]), fmaxf(m_l[2][q], m_l[3][q]));
        float L = 0.f, fac[4];
        #pragma unroll
        for (int w2 = 0; w2 < 4; ++w2) {
            fac[w2] = __builtin_amdgcn_exp2f(m_l[w2][q] - M);
            L += l_l[w2][q] * fac[w2];
        }
        float ov[4];
        #pragma unroll
        for (int j = 0; j < 4; ++j) {
            const int d = d2 * 4 + j;
            float o = 0.f;
            #pragma unroll
            for (int w2 = 0; w2 < 4; ++w2) o += o_lds[w2][d][q] * fac[w2];
            ov[j] = o;               // un-normalized; merge2 applies 1/L + relu
        }
        const size_t pbase = (((size_t)half * 8 + bh) * 128 + qg) * 1024 + q * 32 + d2 * 4;
        *reinterpret_cast<float4*>(partO + pbase) = make_float4(ov[0], ov[1], ov[2], ov[3]);
        if (d2 == 0) {
            const size_t sbase = (((size_t)half * 8 + bh) * 128 + qg) * 32 + q;
            partM[sbase] = M;
            partL[sbase] = L;
        }
    }
}

// ---------------- Kernel D: merge the two key-half partials, normalize, relu ----------------
__global__ __launch_bounds__(256) void merge2(const float* __restrict__ partO,
                                              const float* __restrict__ partM,
                                              const float* __restrict__ partL,
                                              float* __restrict__ out) {
    const int bid = blockIdx.x;      // 1024 = 8 bh * 128 qg
    const int bh = bid >> 7, qg = bid & 127;
    const int b = bh >> 2, h = bh & 3;
    const int t = threadIdx.x;
    const int q = t >> 3, d2 = t & 7;
    const size_t p0 = (((size_t)0 * 8 + bh) * 128 + qg) * 1024 + q * 32 + d2 * 4;
    const size_t p1 = (((size_t)1 * 8 + bh) * 128 + qg) * 1024 + q * 32 + d2 * 4;
    const size_t s0 = (((size_t)0 * 8 + bh) * 128 + qg) * 32 + q;
    const size_t s1 = (((size_t)1 * 8 + bh) * 128 + qg) * 32 + q;
    const float m0 = partM[s0], m1 = partM[s1];
    const float l0 = partL[s0], l1 = partL[s1];
    const float M = fmaxf(m0, m1);
    const float f0 = __builtin_amdgcn_exp2f(m0 - M);
    const float f1 = __builtin_amdgcn_exp2f(m1 - M);
    const float inv = 1.f / (l0 * f0 + l1 * f1);
    const float4 o0 = *reinterpret_cast<const float4*>(partO + p0);
    const float4 o1 = *reinterpret_cast<const float4*>(partO + p1);
    float4 o;
    o.x = fmaxf((o0.x * f0 + o1.x * f1) * inv, 0.f);
    o.y = fmaxf((o0.y * f0 + o1.y * f1) * inv, 0.f);
    o.z = fmaxf((o0.z * f0 + o1.z * f1) * inv, 0.f);
    o.w = fmaxf((o0.w * f0 + o1.w * f1) * inv, 0.f);
    *reinterpret_cast<float4*>(out + ((size_t)(b * N_ + qg * 32 + q) * H_ + h) * D_ + d2 * 4) = o;
}

extern "C" void kernel_launch(void* const* d_in, const int* in_sizes, int n_in,
                              void* d_out, int out_size, void* d_ws, size_t ws_size,
                              hipStream_t stream) {
    // inputs: vt, x, adj, fc_w, fc_b, Q1, Q2, K, V (all fp32)
    const float* x    = (const float*)d_in[1];
    const float* adj  = (const float*)d_in[2];
    const float* fc_w = (const float*)d_in[3];
    const float* fc_b = (const float*)d_in[4];
    const float* Q1   = (const float*)d_in[5];
    const float* Q2   = (const float*)d_in[6];
    const float* K    = (const float*)d_in[7];
    const float* V    = (const float*)d_in[8];
    float* out = (float*)d_out;

    char* ws = (char*)d_ws;
    const size_t MB = 1024 * 1024;
    unsigned short* QtH = (unsigned short*)(ws);             // 2 MB each
    unsigned short* QtL = (unsigned short*)(ws + 2 * MB);
    unsigned short* KtH = (unsigned short*)(ws + 4 * MB);
    unsigned short* KtL = (unsigned short*)(ws + 6 * MB);
    unsigned short* Vt  = (unsigned short*)(ws + 8 * MB);
    unsigned short* VtT = (unsigned short*)(ws + 10 * MB);
    unsigned*     maskb = (unsigned*)    (ws + 12 * MB);     // 2 MB
    float*        fc_wT = (float*)       (ws + 14 * MB);     // 32 KB
    float*        partO = (float*)       (ws + 15 * MB);     // 8 MB: [15, 23) MB
    float*        partM = (float*)       (ws + 23 * MB);     // 256 KB: [23, 23.25) MB
    float*        partL = (float*)       (ws + 23 * MB + 262144); // 256 KB: [23.25, 23.5) MB

    hipLaunchKernelGGL(prep_fcT, dim3(32), dim3(256), 0, stream, fc_w, fc_wT);
    hipLaunchKernelGGL(pack_adj, dim3(N_ * N_ / 256), dim3(256), 0, stream, adj, maskb);
    hipLaunchKernelGGL(proj_kernel, dim3(B_ * N_ / 8), dim3(128), 0, stream,
                       x, fc_wT, fc_b, Q1, Q2, K, V, QtH, QtL, KtH, KtL, Vt);
    hipLaunchKernelGGL(vtrans, dim3(8 * (N_ / 64)), dim3(256), 0, stream, Vt, VtT);
    hipLaunchKernelGGL(flash_part, dim3(2048), dim3(256), 0, stream,
                       QtH, QtL, KtH, KtL, VtT, maskb, partO, partM, partL);
    hipLaunchKernelGGL(merge2, dim3(1024), dim3(256), 0, stream, partO, partM, partL, out);
}

// Round 11
// 131.288 us; speedup vs baseline: 1.3636x; 1.3636x over previous
//
#include <hip/hip_runtime.h>
#include <hip/hip_bf16.h>

#define NEG_SLOPE_C 0.1f
#define LOG2E_C 1.4426950408889634f
#define NEGB_C (-1.3e16f)            // -9e15 * log2(e), rounded down (log2-domain mask value)

constexpr int B_ = 2, N_ = 4096, IN_ = 64, H_ = 4, D_ = 32;

typedef float f32x16 __attribute__((ext_vector_type(16)));
typedef __bf16 bf16x8 __attribute__((ext_vector_type(8)));

__device__ inline unsigned short f2bfu(float x) {           // RNE f32 -> bf16 bits
    unsigned u = __float_as_uint(x);
    return (unsigned short)((u + 0x7fffu + ((u >> 16) & 1u)) >> 16);
}
__device__ inline float bfu2f(unsigned short s) { return __uint_as_float(((unsigned)s) << 16); }
__device__ inline bf16x8 ld_bf8(const unsigned short* p) {
    uint4 r = *reinterpret_cast<const uint4*>(p);
    return __builtin_bit_cast(bf16x8, r);
}

// -------- Kernel P: transpose fc_w [128][64] -> fc_wT [64][128] (32 KB, trivial) --------
__global__ __launch_bounds__(256) void prep_fcT(const float* __restrict__ fc_w,
                                                float* __restrict__ fc_wT) {
    int t = blockIdx.x * 256 + threadIdx.x;   // 8192 threads
    int c = t >> 6, k = t & 63;
    fc_wT[k * 128 + c] = fc_w[c * 64 + k];
}

// ---------- Kernel A (r1-proven): adj -> maskb[q*(N/32) + kchunk], bit j = adj[q][kchunk*32+j] ----------
__global__ __launch_bounds__(256) void pack_adj(const float* __restrict__ adj,
                                                unsigned* __restrict__ maskbits) {
    long long idx = (long long)blockIdx.x * blockDim.x + threadIdx.x;
    float a = adj[idx];
    unsigned long long ball = __ballot(a != 0.0f);
    int lane = threadIdx.x & 63;
    if (lane == 0)       maskbits[idx >> 5] = (unsigned)(ball & 0xffffffffULL);
    else if (lane == 32) maskbits[idx >> 5] = (unsigned)(ball >> 32);
}

// ------------- Kernel B: projections -> bf16 hi/lo splits + V row-major (bf16) -------------
__global__ __launch_bounds__(128) void proj_kernel(
    const float* __restrict__ x, const float* __restrict__ fc_wT,
    const float* __restrict__ fc_b, const float* __restrict__ Q1,
    const float* __restrict__ Q2, const float* __restrict__ K,
    const float* __restrict__ V,
    unsigned short* __restrict__ QtH, unsigned short* __restrict__ QtL,
    unsigned short* __restrict__ KtH, unsigned short* __restrict__ KtL,
    unsigned short* __restrict__ Vt) {
    const int t = threadIdx.x;          // 0..127
    const int h = t >> 5, e = t & 31;
    const float* q1p = Q1 + h * D_ * D_;
    const float* q2p = Q2 + h * D_ * D_;
    const float* kp  = K  + h * D_ * D_;
    const float* vp  = V  + h * D_ * D_;
    __shared__ float xr[IN_];
    __shared__ float xp[H_ * D_];
    const float bias = fc_b[t];
    for (int rr = 0; rr < 8; ++rr) {
        const int bn = blockIdx.x * 8 + rr;   // 0..B*N-1
        const int b = bn / N_, n = bn % N_;
        if (t < IN_) xr[t] = x[(long long)bn * IN_ + t];
        __syncthreads();
        float acc = bias;
        #pragma unroll
        for (int k = 0; k < IN_; ++k) acc += xr[k] * fc_wT[k * 128 + t];  // coalesced, L1-hit
        xp[t] = acc;
        __syncthreads();
        const float* xph = xp + h * D_;
        float a1 = 0.f, a2 = 0.f, ak = 0.f, av = 0.f;
        #pragma unroll
        for (int d = 0; d < D_; ++d) {
            float xv = xph[d];
            a1 += xv * q1p[d * D_ + e];
            a2 += xv * q2p[d * D_ + e];
            ak += xv * kp [d * D_ + e];
            av += xv * vp [d * D_ + e];
        }
        float q = a1 + a2;
        q = q >= 0.f ? q : NEG_SLOPE_C * q;   // Qt = leaky(Qt1+Qt2)
        size_t o = ((size_t)(b * H_ + h) * N_ + n) * D_ + e;
        unsigned short qh = f2bfu(q);
        QtH[o] = qh;
        QtL[o] = f2bfu(q - bfu2f(qh));
        unsigned short kh = f2bfu(ak);
        KtH[o] = kh;
        KtL[o] = f2bfu(ak - bfu2f(kh));
        Vt[o]  = f2bfu(av);                   // row-major, coalesced
        __syncthreads();
    }
}

// ------------- Kernel B2: Vt [bh][n][d] -> VtT [bh][d][n] (LDS tile transpose) -------------
__global__ __launch_bounds__(256) void vtrans(const unsigned short* __restrict__ Vt,
                                              unsigned short* __restrict__ VtT) {
    const int bh = blockIdx.x >> 6;
    const int n0 = (blockIdx.x & 63) * 64;
    __shared__ unsigned short tile[64][34];
    const int t = threadIdx.x;
    {
        const int r = t >> 2, c = (t & 3) * 8;
        uint4 v = *reinterpret_cast<const uint4*>(Vt + ((size_t)bh * N_ + n0 + r) * D_ + c);
        *reinterpret_cast<uint4*>(&tile[r][c]) = v;
    }
    __syncthreads();
    {
        const int d = t >> 3, nc = (t & 7) * 8;
        unsigned short tmp[8];
        #pragma unroll
        for (int j = 0; j < 8; ++j) tmp[j] = tile[nc + j][d];
        *reinterpret_cast<uint4*>(VtT + ((size_t)bh * D_ + d) * N_ + n0 + nc) =
            *reinterpret_cast<uint4*>(tmp);
    }
}

// ---------------- Kernel C: MFMA flash attention PARTIAL (2 blocks per query-group) ----------------
// grid 2048: (bh, qg, half). 4 waves/block, each wave = 512-key strip; block LDS-merges its
// 4 strips and writes un-normalized partial (O, m, l) to ws.
// launch_bounds (256,4): loose VGPR budget (128) so the 6 in-flight ld_bf8 keep their own
// destination registers -> memory-level parallelism preserved (r10's (256,8) squeezed VGPR
// to 32 and serialized the loads: 145us, VALUBusy 31%).
__global__ __launch_bounds__(256, 4) void flash_part(
    const unsigned short* __restrict__ QtH, const unsigned short* __restrict__ QtL,
    const unsigned short* __restrict__ KtH, const unsigned short* __restrict__ KtL,
    const unsigned short* __restrict__ VtT, const unsigned* __restrict__ maskb,
    float* __restrict__ partO, float* __restrict__ partM, float* __restrict__ partL) {
    const int bid = blockIdx.x;      // 2048 blocks
    const int bh = bid >> 8;         // 0..7
    const int qg = (bid >> 1) & 127; // 32-query group
    const int half = bid & 1;        // key half: 0 -> keys 0..2047, 1 -> 2048..4095
    const int t = threadIdx.x;
    const int w = t >> 6;            // wave 0..3
    const int wu = __builtin_amdgcn_readfirstlane(w);
    const int l = t & 63;
    const int lq = l & 31;           // this lane's query column
    const int hi = l >> 5;
    const int q0 = qg * 32;
    const int strip = half * 4 + wu; // 0..7, this wave's 512-key strip

    const size_t bhND = (size_t)bh * N_ * D_;
    // Q B-fragments: B[k=dim][col=q]
    const unsigned short* qbh = QtH + bhND + (size_t)(q0 + lq) * D_ + hi * 8;
    const unsigned short* qbl = QtL + bhND + (size_t)(q0 + lq) * D_ + hi * 8;
    const bf16x8 qh0 = ld_bf8(qbh), qh1 = ld_bf8(qbh + 16);
    const bf16x8 ql0 = ld_bf8(qbl), ql1 = ld_bf8(qbl + 16);

    f32x16 acc = {};                 // O^T: row=d, col=q
    float m_run = -3.0e38f, l_run = 0.f;   // m in log2 units
    const float negb = NEGB_C;
    const float C1 = 0.55f * LOG2E_C, C2 = 0.45f * LOG2E_C;

    const int kw0 = strip * 512;     // this wave's 512-key strip
    const unsigned short* kh_p = KtH + bhND + (size_t)(kw0 + lq) * D_ + hi * 8;
    const unsigned short* kl_p = KtL + bhND + (size_t)(kw0 + lq) * D_ + hi * 8;
    const unsigned short* v_p  = VtT + ((size_t)bh * D_ + lq) * N_ + kw0 + hi * 8;
    // per-lane mask row: this query's key-chunk words (L1-resident, reused across tt)
    const unsigned* mrow = maskb + (size_t)(q0 + lq) * (N_ / 32) + strip * 16;

    for (int tt = 0; tt < 16; ++tt) {
        const unsigned word = mrow[tt];              // 32 key-bits for this lane's query
        const unsigned word_h = word >> (hi * 4);    // pre-shift for this half-wave's row offset
        const bf16x8 kh0v = ld_bf8(kh_p), kh1v = ld_bf8(kh_p + 16);
        const bf16x8 kl0v = ld_bf8(kl_p), kl1v = ld_bf8(kl_p + 16);
        const bf16x8 v0   = ld_bf8(v_p),  v1   = ld_bf8(v_p + 16);
        kh_p += 32 * D_; kl_p += 32 * D_; v_p += 32;

        f32x16 s = {};
        s = __builtin_amdgcn_mfma_f32_32x32x16_bf16(kh0v, qh0, s, 0, 0, 0);
        s = __builtin_amdgcn_mfma_f32_32x32x16_bf16(kh1v, qh1, s, 0, 0, 0);
        s = __builtin_amdgcn_mfma_f32_32x32x16_bf16(kh0v, ql0, s, 0, 0, 0);
        s = __builtin_amdgcn_mfma_f32_32x32x16_bf16(kh1v, ql1, s, 0, 0, 0);
        s = __builtin_amdgcn_mfma_f32_32x32x16_bf16(kl0v, qh0, s, 0, 0, 0);
        s = __builtin_amdgcn_mfma_f32_32x32x16_bf16(kl1v, qh1, s, 0, 0, 0);

        // am = log2-scaled leaky score, masked via per-lane bit test
        float am[16];
        #pragma unroll
        for (int r = 0; r < 16; ++r) {
            const int sh = (r & 3) + 8 * (r >> 2);   // key row within half-wave, compile-time
            const float v = s[r];
            const float a = fmaf(C2, fabsf(v), C1 * v);
            am[r] = ((word_h >> sh) & 1u) ? a : negb;
        }
        // row max, cross-half via shfl_xor (r5-proven path)
        const float x0 = fmaxf(fmaxf(am[0], am[1]), am[2]);
        const float x1 = fmaxf(fmaxf(am[3], am[4]), am[5]);
        const float x2 = fmaxf(fmaxf(am[6], am[7]), am[8]);
        const float x3 = fmaxf(fmaxf(am[9], am[10]), am[11]);
        const float x4 = fmaxf(fmaxf(am[12], am[13]), am[14]);
        const float y0 = fmaxf(fmaxf(x0, x1), x2);
        const float y1 = fmaxf(fmaxf(x3, x4), am[15]);
        float cmax = fmaxf(y0, y1);
        cmax = fmaxf(cmax, __shfl_xor(cmax, 32));
        if (!__all(cmax <= m_run)) {
            const float nm = fmaxf(m_run, cmax);
            const float sc = __builtin_amdgcn_exp2f(m_run - nm);
            l_run *= sc;
            #pragma unroll
            for (int r = 0; r < 16; ++r) acc[r] *= sc;
            m_run = nm;
        }
        float e[16];
        #pragma unroll
        for (int r = 0; r < 16; ++r) e[r] = __builtin_amdgcn_exp2f(am[r] - m_run);
        const float s0 = (e[0] + e[1]) + (e[2] + e[3]);
        const float s1 = (e[4] + e[5]) + (e[6] + e[7]);
        const float s2 = (e[8] + e[9]) + (e[10] + e[11]);
        const float s3 = (e[12] + e[13]) + (e[14] + e[15]);
        float lsum = (s0 + s1) + (s2 + s3);
        lsum += __shfl_xor(lsum, 32);
        l_run += lsum;
        // P -> bf16 pairs: 8 cvt_pk + 4 permlane32_swap (distinct operands -> safe; proven)
        unsigned c0w, c1w, c2w, c3w, c4w, c5w, c6w, c7w;
        asm("v_cvt_pk_bf16_f32 %0, %1, %2" : "=v"(c0w) : "v"(e[0]),  "v"(e[1]));
        asm("v_cvt_pk_bf16_f32 %0, %1, %2" : "=v"(c1w) : "v"(e[2]),  "v"(e[3]));
        asm("v_cvt_pk_bf16_f32 %0, %1, %2" : "=v"(c2w) : "v"(e[4]),  "v"(e[5]));
        asm("v_cvt_pk_bf16_f32 %0, %1, %2" : "=v"(c3w) : "v"(e[6]),  "v"(e[7]));
        asm("v_cvt_pk_bf16_f32 %0, %1, %2" : "=v"(c4w) : "v"(e[8]),  "v"(e[9]));
        asm("v_cvt_pk_bf16_f32 %0, %1, %2" : "=v"(c5w) : "v"(e[10]), "v"(e[11]));
        asm("v_cvt_pk_bf16_f32 %0, %1, %2" : "=v"(c6w) : "v"(e[12]), "v"(e[13]));
        asm("v_cvt_pk_bf16_f32 %0, %1, %2" : "=v"(c7w) : "v"(e[14]), "v"(e[15]));
        asm("v_permlane32_swap_b32 %0, %1" : "+v"(c0w), "+v"(c2w));
        asm("v_permlane32_swap_b32 %0, %1" : "+v"(c1w), "+v"(c3w));
        asm("v_permlane32_swap_b32 %0, %1" : "+v"(c4w), "+v"(c6w));
        asm("v_permlane32_swap_b32 %0, %1" : "+v"(c5w), "+v"(c7w));
        const uint4 b0u = make_uint4(c0w, c1w, c2w, c3w);
        const uint4 b1u = make_uint4(c4w, c5w, c6w, c7w);
        acc = __builtin_amdgcn_mfma_f32_32x32x16_bf16(v0, __builtin_bit_cast(bf16x8, b0u), acc, 0, 0, 0);
        acc = __builtin_amdgcn_mfma_f32_32x32x16_bf16(v1, __builtin_bit_cast(bf16x8, b1u), acc, 0, 0, 0);
    }

    // ---- cross-wave flash merge (4 strip partials) -> un-normalized block partial ----
    __shared__ float o_lds[4][32][33];
    __shared__ float m_l[4][32];
    __shared__ float l_l[4][32];
    if (hi == 0) { m_l[w][lq] = m_run; l_l[w][lq] = l_run; }
    #pragma unroll
    for (int r = 0; r < 16; ++r) {
        const int d = (r & 3) + 8 * (r >> 2) + 4 * hi;
        o_lds[w][d][lq] = acc[r];
    }
    __syncthreads();
    {
        const int q = t >> 3;        // 0..31
        const int d2 = t & 7;        // d = d2*4 .. d2*4+3 (consecutive lanes -> consecutive 16B)
        const float M = fmaxf(fmaxf(m_l[0][q], m_l[1][q]), fmaxf(m_l[2][q], m_l[3][q]));
        float L = 0.f, fac[4];
        #pragma unroll
        for (int w2 = 0; w2 < 4; ++w2) {
            fac[w2] = __builtin_amdgcn_exp2f(m_l[w2][q] - M);
            L += l_l[w2][q] * fac[w2];
        }
        float ov[4];
        #pragma unroll
        for (int j = 0; j < 4; ++j) {
            const int d = d2 * 4 + j;
            float o = 0.f;
            #pragma unroll
            for (int w2 = 0; w2 < 4; ++w2) o += o_lds[w2][d][q] * fac[w2];
            ov[j] = o;               // un-normalized; merge2 applies 1/L + relu
        }
        const size_t pbase = (((size_t)half * 8 + bh) * 128 + qg) * 1024 + q * 32 + d2 * 4;
        *reinterpret_cast<float4*>(partO + pbase) = make_float4(ov[0], ov[1], ov[2], ov[3]);
        if (d2 == 0) {
            const size_t sbase = (((size_t)half * 8 + bh) * 128 + qg) * 32 + q;
            partM[sbase] = M;
            partL[sbase] = L;
        }
    }
}

// ---------------- Kernel D: merge the two key-half partials, normalize, relu ----------------
__global__ __launch_bounds__(256) void merge2(const float* __restrict__ partO,
                                              const float* __restrict__ partM,
                                              const float* __restrict__ partL,
                                              float* __restrict__ out) {
    const int bid = blockIdx.x;      // 1024 = 8 bh * 128 qg
    const int bh = bid >> 7, qg = bid & 127;
    const int b = bh >> 2, h = bh & 3;
    const int t = threadIdx.x;
    const int q = t >> 3, d2 = t & 7;
    const size_t p0 = (((size_t)0 * 8 + bh) * 128 + qg) * 1024 + q * 32 + d2 * 4;
    const size_t p1 = (((size_t)1 * 8 + bh) * 128 + qg) * 1024 + q * 32 + d2 * 4;
    const size_t s0 = (((size_t)0 * 8 + bh) * 128 + qg) * 32 + q;
    const size_t s1 = (((size_t)1 * 8 + bh) * 128 + qg) * 32 + q;
    const float m0 = partM[s0], m1 = partM[s1];
    const float l0 = partL[s0], l1 = partL[s1];
    const float M = fmaxf(m0, m1);
    const float f0 = __builtin_amdgcn_exp2f(m0 - M);
    const float f1 = __builtin_amdgcn_exp2f(m1 - M);
    const float inv = 1.f / (l0 * f0 + l1 * f1);
    const float4 o0 = *reinterpret_cast<const float4*>(partO + p0);
    const float4 o1 = *reinterpret_cast<const float4*>(partO + p1);
    float4 o;
    o.x = fmaxf((o0.x * f0 + o1.x * f1) * inv, 0.f);
    o.y = fmaxf((o0.y * f0 + o1.y * f1) * inv, 0.f);
    o.z = fmaxf((o0.z * f0 + o1.z * f1) * inv, 0.f);
    o.w = fmaxf((o0.w * f0 + o1.w * f1) * inv, 0.f);
    *reinterpret_cast<float4*>(out + ((size_t)(b * N_ + qg * 32 + q) * H_ + h) * D_ + d2 * 4) = o;
}

extern "C" void kernel_launch(void* const* d_in, const int* in_sizes, int n_in,
                              void* d_out, int out_size, void* d_ws, size_t ws_size,
                              hipStream_t stream) {
    // inputs: vt, x, adj, fc_w, fc_b, Q1, Q2, K, V (all fp32)
    const float* x    = (const float*)d_in[1];
    const float* adj  = (const float*)d_in[2];
    const float* fc_w = (const float*)d_in[3];
    const float* fc_b = (const float*)d_in[4];
    const float* Q1   = (const float*)d_in[5];
    const float* Q2   = (const float*)d_in[6];
    const float* K    = (const float*)d_in[7];
    const float* V    = (const float*)d_in[8];
    float* out = (float*)d_out;

    char* ws = (char*)d_ws;
    const size_t MB = 1024 * 1024;
    unsigned short* QtH = (unsigned short*)(ws);             // 2 MB each
    unsigned short* QtL = (unsigned short*)(ws + 2 * MB);
    unsigned short* KtH = (unsigned short*)(ws + 4 * MB);
    unsigned short* KtL = (unsigned short*)(ws + 6 * MB);
    unsigned short* Vt  = (unsigned short*)(ws + 8 * MB);
    unsigned short* VtT = (unsigned short*)(ws + 10 * MB);
    unsigned*     maskb = (unsigned*)    (ws + 12 * MB);     // 2 MB
    float*        fc_wT = (float*)       (ws + 14 * MB);     // 32 KB
    float*        partO = (float*)       (ws + 15 * MB);     // 8 MB: [15, 23) MB
    float*        partM = (float*)       (ws + 23 * MB);     // 256 KB: [23, 23.25) MB
    float*        partL = (float*)       (ws + 23 * MB + 262144); // 256 KB: [23.25, 23.5) MB

    hipLaunchKernelGGL(prep_fcT, dim3(32), dim3(256), 0, stream, fc_w, fc_wT);
    hipLaunchKernelGGL(pack_adj, dim3(N_ * N_ / 256), dim3(256), 0, stream, adj, maskb);
    hipLaunchKernelGGL(proj_kernel, dim3(B_ * N_ / 8), dim3(128), 0, stream,
                       x, fc_wT, fc_b, Q1, Q2, K, V, QtH, QtL, KtH, KtL, Vt);
    hipLaunchKernelGGL(vtrans, dim3(8 * (N_ / 64)), dim3(256), 0, stream, Vt, VtT);
    hipLaunchKernelGGL(flash_part, dim3(2048), dim3(256), 0, stream,
                       QtH, QtL, KtH, KtL, VtT, maskb, partO, partM, partL);
    hipLaunchKernelGGL(merge2, dim3(1024), dim3(256), 0, stream, partO, partM, partL, out);
}

// Round 12
// 123.354 us; speedup vs baseline: 1.4513x; 1.0643x over previous
//
#include <hip/hip_runtime.h>
#include <hip/hip_bf16.h>

#define NEG_SLOPE_C 0.1f
#define LOG2E_C 1.4426950408889634f
#define NEGB_C (-1.3e16f)            // -9e15 * log2(e), rounded down (log2-domain mask value)

constexpr int B_ = 2, N_ = 4096, IN_ = 64, H_ = 4, D_ = 32;

typedef float f32x16 __attribute__((ext_vector_type(16)));
typedef __bf16 bf16x8 __attribute__((ext_vector_type(8)));

__device__ inline unsigned short f2bfu(float x) {           // RNE f32 -> bf16 bits
    unsigned u = __float_as_uint(x);
    return (unsigned short)((u + 0x7fffu + ((u >> 16) & 1u)) >> 16);
}
__device__ inline float bfu2f(unsigned short s) { return __uint_as_float(((unsigned)s) << 16); }
__device__ inline bf16x8 ld_bf8(const unsigned short* p) {
    uint4 r = *reinterpret_cast<const uint4*>(p);
    return __builtin_bit_cast(bf16x8, r);
}

// -------- Kernel P: transpose fc_w [128][64] -> fc_wT [64][128] (32 KB, trivial) --------
__global__ __launch_bounds__(256) void prep_fcT(const float* __restrict__ fc_w,
                                                float* __restrict__ fc_wT) {
    int t = blockIdx.x * 256 + threadIdx.x;   // 8192 threads
    int c = t >> 6, k = t & 63;
    fc_wT[k * 128 + c] = fc_w[c * 64 + k];
}

// ---- Kernel A: adj -> lane-coalesced mask: maskL[((qg*8+strip)*16+tt)*32 + (q&31)] ----
// word bit j = adj[q][(strip*16+tt)*32 + j] != 0. Ballot logic identical to the proven r1 pack;
// only the output index changed (flash reads lanes-contiguous 128B per tile).
__global__ __launch_bounds__(256) void pack_adjL(const float* __restrict__ adj,
                                                 unsigned* __restrict__ maskL) {
    long long idx = (long long)blockIdx.x * blockDim.x + threadIdx.x;
    float a = adj[idx];
    unsigned long long ball = __ballot(a != 0.0f);
    int lane = threadIdx.x & 63;
    unsigned word = 0; bool wr = false;
    if (lane == 0)       { word = (unsigned)(ball & 0xffffffffULL); wr = true; }
    else if (lane == 32) { word = (unsigned)(ball >> 32);           wr = true; }
    if (wr) {
        const long long widx = idx >> 5;         // q*128 + kc
        const int q  = (int)(widx >> 7);
        const int kc = (int)(widx & 127);
        const int qg = q >> 5, lq = q & 31;
        const int strip = kc >> 4, tt = kc & 15;
        maskL[(((size_t)(qg * 8 + strip) * 16) + tt) * 32 + lq] = word;
    }
}

// ------------- Kernel B: projections -> bf16 hi/lo splits + V row-major (bf16) -------------
__global__ __launch_bounds__(128) void proj_kernel(
    const float* __restrict__ x, const float* __restrict__ fc_wT,
    const float* __restrict__ fc_b, const float* __restrict__ Q1,
    const float* __restrict__ Q2, const float* __restrict__ K,
    const float* __restrict__ V,
    unsigned short* __restrict__ QtH, unsigned short* __restrict__ QtL,
    unsigned short* __restrict__ KtH, unsigned short* __restrict__ KtL,
    unsigned short* __restrict__ Vt) {
    const int t = threadIdx.x;          // 0..127
    const int h = t >> 5, e = t & 31;
    const float* q1p = Q1 + h * D_ * D_;
    const float* q2p = Q2 + h * D_ * D_;
    const float* kp  = K  + h * D_ * D_;
    const float* vp  = V  + h * D_ * D_;
    __shared__ float xr[IN_];
    __shared__ float xp[H_ * D_];
    const float bias = fc_b[t];
    for (int rr = 0; rr < 8; ++rr) {
        const int bn = blockIdx.x * 8 + rr;   // 0..B*N-1
        const int b = bn / N_, n = bn % N_;
        if (t < IN_) xr[t] = x[(long long)bn * IN_ + t];
        __syncthreads();
        float acc = bias;
        #pragma unroll
        for (int k = 0; k < IN_; ++k) acc += xr[k] * fc_wT[k * 128 + t];  // coalesced, L1-hit
        xp[t] = acc;
        __syncthreads();
        const float* xph = xp + h * D_;
        float a1 = 0.f, a2 = 0.f, ak = 0.f, av = 0.f;
        #pragma unroll
        for (int d = 0; d < D_; ++d) {
            float xv = xph[d];
            a1 += xv * q1p[d * D_ + e];
            a2 += xv * q2p[d * D_ + e];
            ak += xv * kp [d * D_ + e];
            av += xv * vp [d * D_ + e];
        }
        float q = a1 + a2;
        q = q >= 0.f ? q : NEG_SLOPE_C * q;   // Qt = leaky(Qt1+Qt2)
        size_t o = ((size_t)(b * H_ + h) * N_ + n) * D_ + e;
        unsigned short qh = f2bfu(q);
        QtH[o] = qh;
        QtL[o] = f2bfu(q - bfu2f(qh));
        unsigned short kh = f2bfu(ak);
        KtH[o] = kh;
        KtL[o] = f2bfu(ak - bfu2f(kh));
        Vt[o]  = f2bfu(av);                   // row-major, coalesced
        __syncthreads();
    }
}

// ------------- Kernel B2: Vt [bh][n][d] -> VtT [bh][d][n] (LDS tile transpose) -------------
__global__ __launch_bounds__(256) void vtrans(const unsigned short* __restrict__ Vt,
                                              unsigned short* __restrict__ VtT) {
    const int bh = blockIdx.x >> 6;
    const int n0 = (blockIdx.x & 63) * 64;
    __shared__ unsigned short tile[64][34];
    const int t = threadIdx.x;
    {
        const int r = t >> 2, c = (t & 3) * 8;
        uint4 v = *reinterpret_cast<const uint4*>(Vt + ((size_t)bh * N_ + n0 + r) * D_ + c);
        *reinterpret_cast<uint4*>(&tile[r][c]) = v;
    }
    __syncthreads();
    {
        const int d = t >> 3, nc = (t & 7) * 8;
        unsigned short tmp[8];
        #pragma unroll
        for (int j = 0; j < 8; ++j) tmp[j] = tile[nc + j][d];
        *reinterpret_cast<uint4*>(VtT + ((size_t)bh * D_ + d) * N_ + n0 + nc) =
            *reinterpret_cast<uint4*>(tmp);
    }
}

// ---------------- Kernel C: MFMA flash attention, 32 queries/block, 8-way key split ----------------
// r7 geometry (512 thr, in-block 8-way merge) + 2-deep software-pipelined K/mask loads +
// lane-coalesced per-lane mask test. launch_bounds (512,4): 128-reg budget = 2 blocks/CU.
__global__ __launch_bounds__(512, 4) void flash_mfma(
    const unsigned short* __restrict__ QtH, const unsigned short* __restrict__ QtL,
    const unsigned short* __restrict__ KtH, const unsigned short* __restrict__ KtL,
    const unsigned short* __restrict__ VtT, const unsigned* __restrict__ maskL,
    float* __restrict__ out) {
    const int bid = blockIdx.x;      // 1024 blocks
    const int bh = bid >> 7;         // 0..7
    const int qg = bid & 127;        // 32-query group
    const int b = bh >> 2, h = bh & 3;
    const int t = threadIdx.x;
    const int w = t >> 6;            // key-split wave 0..7
    const int wu = __builtin_amdgcn_readfirstlane(w);
    const int l = t & 63;
    const int lq = l & 31;           // this lane's query column
    const int hi = l >> 5;
    const int q0 = qg * 32;

    const size_t bhND = (size_t)bh * N_ * D_;
    // Q B-fragments: B[k=dim][col=q]
    const unsigned short* qbh = QtH + bhND + (size_t)(q0 + lq) * D_ + hi * 8;
    const unsigned short* qbl = QtL + bhND + (size_t)(q0 + lq) * D_ + hi * 8;
    const bf16x8 qh0 = ld_bf8(qbh), qh1 = ld_bf8(qbh + 16);
    const bf16x8 ql0 = ld_bf8(qbl), ql1 = ld_bf8(qbl + 16);

    f32x16 acc = {};                 // O^T: row=d, col=q
    float m_run = -3.0e38f, l_run = 0.f;   // m in log2 units
    const float negb = NEGB_C;
    const float C1 = 0.55f * LOG2E_C, C2 = 0.45f * LOG2E_C;

    const int kw0 = wu * 512;        // this wave's 512-key strip
    const unsigned short* kh_p = KtH + bhND + (size_t)(kw0 + lq) * D_ + hi * 8;
    const unsigned short* kl_p = KtL + bhND + (size_t)(kw0 + lq) * D_ + hi * 8;
    const unsigned short* v_p  = VtT + ((size_t)bh * D_ + lq) * N_ + kw0 + hi * 8;
    // lane-coalesced mask: one dword per lane per tile, lanes contiguous (128B/tile/wave)
    const unsigned* ml_p = maskL + ((size_t)(qg * 8 + wu) * 16) * 32 + lq;

    // QK^T for one 32-key tile: 3-term bf16 split (hi*hi, hi*lo, lo*hi)
    auto qk6 = [&](const bf16x8& a0, const bf16x8& a1,
                   const bf16x8& b0, const bf16x8& b1) -> f32x16 {
        f32x16 s = {};
        s = __builtin_amdgcn_mfma_f32_32x32x16_bf16(a0, qh0, s, 0, 0, 0);
        s = __builtin_amdgcn_mfma_f32_32x32x16_bf16(a1, qh1, s, 0, 0, 0);
        s = __builtin_amdgcn_mfma_f32_32x32x16_bf16(a0, ql0, s, 0, 0, 0);
        s = __builtin_amdgcn_mfma_f32_32x32x16_bf16(a1, ql1, s, 0, 0, 0);
        s = __builtin_amdgcn_mfma_f32_32x32x16_bf16(b0, qh0, s, 0, 0, 0);
        s = __builtin_amdgcn_mfma_f32_32x32x16_bf16(b1, qh1, s, 0, 0, 0);
        return s;
    };

    // softmax + PV for one tile; V loaded here (issued ~250cy before PV consumes it)
    auto softpv = [&](const f32x16& s, unsigned word) {
        const bf16x8 v0 = ld_bf8(v_p), v1 = ld_bf8(v_p + 16); v_p += 32;
        const unsigned word_h = word >> (hi * 4);
        float am[16];
        #pragma unroll
        for (int r = 0; r < 16; ++r) {
            const int sh = (r & 3) + 8 * (r >> 2);   // key row within half-wave, compile-time
            const float vv = s[r];
            const float aa = fmaf(C2, fabsf(vv), C1 * vv);
            am[r] = ((word_h >> sh) & 1u) ? aa : negb;
        }
        const float x0 = fmaxf(fmaxf(am[0], am[1]), am[2]);
        const float x1 = fmaxf(fmaxf(am[3], am[4]), am[5]);
        const float x2 = fmaxf(fmaxf(am[6], am[7]), am[8]);
        const float x3 = fmaxf(fmaxf(am[9], am[10]), am[11]);
        const float x4 = fmaxf(fmaxf(am[12], am[13]), am[14]);
        const float y0 = fmaxf(fmaxf(x0, x1), x2);
        const float y1 = fmaxf(fmaxf(x3, x4), am[15]);
        float cmax = fmaxf(y0, y1);
        cmax = fmaxf(cmax, __shfl_xor(cmax, 32));
        if (!__all(cmax <= m_run)) {
            const float nm = fmaxf(m_run, cmax);
            const float sc = __builtin_amdgcn_exp2f(m_run - nm);
            l_run *= sc;
            #pragma unroll
            for (int r = 0; r < 16; ++r) acc[r] *= sc;
            m_run = nm;
        }
        float e[16];
        #pragma unroll
        for (int r = 0; r < 16; ++r) e[r] = __builtin_amdgcn_exp2f(am[r] - m_run);
        const float s0 = (e[0] + e[1]) + (e[2] + e[3]);
        const float s1 = (e[4] + e[5]) + (e[6] + e[7]);
        const float s2 = (e[8] + e[9]) + (e[10] + e[11]);
        const float s3 = (e[12] + e[13]) + (e[14] + e[15]);
        float lsum = (s0 + s1) + (s2 + s3);
        lsum += __shfl_xor(lsum, 32);
        l_run += lsum;
        unsigned c0w, c1w, c2w, c3w, c4w, c5w, c6w, c7w;
        asm("v_cvt_pk_bf16_f32 %0, %1, %2" : "=v"(c0w) : "v"(e[0]),  "v"(e[1]));
        asm("v_cvt_pk_bf16_f32 %0, %1, %2" : "=v"(c1w) : "v"(e[2]),  "v"(e[3]));
        asm("v_cvt_pk_bf16_f32 %0, %1, %2" : "=v"(c2w) : "v"(e[4]),  "v"(e[5]));
        asm("v_cvt_pk_bf16_f32 %0, %1, %2" : "=v"(c3w) : "v"(e[6]),  "v"(e[7]));
        asm("v_cvt_pk_bf16_f32 %0, %1, %2" : "=v"(c4w) : "v"(e[8]),  "v"(e[9]));
        asm("v_cvt_pk_bf16_f32 %0, %1, %2" : "=v"(c5w) : "v"(e[10]), "v"(e[11]));
        asm("v_cvt_pk_bf16_f32 %0, %1, %2" : "=v"(c6w) : "v"(e[12]), "v"(e[13]));
        asm("v_cvt_pk_bf16_f32 %0, %1, %2" : "=v"(c7w) : "v"(e[14]), "v"(e[15]));
        asm("v_permlane32_swap_b32 %0, %1" : "+v"(c0w), "+v"(c2w));
        asm("v_permlane32_swap_b32 %0, %1" : "+v"(c1w), "+v"(c3w));
        asm("v_permlane32_swap_b32 %0, %1" : "+v"(c4w), "+v"(c6w));
        asm("v_permlane32_swap_b32 %0, %1" : "+v"(c5w), "+v"(c7w));
        const uint4 b0u = make_uint4(c0w, c1w, c2w, c3w);
        const uint4 b1u = make_uint4(c4w, c5w, c6w, c7w);
        acc = __builtin_amdgcn_mfma_f32_32x32x16_bf16(v0, __builtin_bit_cast(bf16x8, b0u), acc, 0, 0, 0);
        acc = __builtin_amdgcn_mfma_f32_32x32x16_bf16(v1, __builtin_bit_cast(bf16x8, b1u), acc, 0, 0, 0);
    };

    // ---- 2-deep pipelined main loop: loads for tile t+2 issue before softmax(t) ----
    // prefetch tiles 0 and 1 (named A/B register sets, static indexing)
    bf16x8 Akh0 = ld_bf8(kh_p), Akh1 = ld_bf8(kh_p + 16);
    bf16x8 Akl0 = ld_bf8(kl_p), Akl1 = ld_bf8(kl_p + 16);
    unsigned Amw = ml_p[0];
    kh_p += 32 * D_; kl_p += 32 * D_;
    bf16x8 Bkh0 = ld_bf8(kh_p), Bkh1 = ld_bf8(kh_p + 16);
    bf16x8 Bkl0 = ld_bf8(kl_p), Bkl1 = ld_bf8(kl_p + 16);
    unsigned Bmw = ml_p[32];
    kh_p += 32 * D_; kl_p += 32 * D_;

    for (int it = 0; it < 8; ++it) {
        // even tile 2it
        const unsigned mwE = Amw;
        const f32x16 sE = qk6(Akh0, Akh1, Akl0, Akl1);      // reads A, then A refilled below
        Akh0 = ld_bf8(kh_p); Akh1 = ld_bf8(kh_p + 16);       // prefetch tile 2it+2
        Akl0 = ld_bf8(kl_p); Akl1 = ld_bf8(kl_p + 16);       // (last iter overruns into
        Amw  = ml_p[(2 * it + 2) * 32];                      //  adjacent ws memory; unused)
        kh_p += 32 * D_; kl_p += 32 * D_;
        softpv(sE, mwE);                                     // ~300cy VALU covers the loads
        // odd tile 2it+1
        const unsigned mwO = Bmw;
        const f32x16 sO = qk6(Bkh0, Bkh1, Bkl0, Bkl1);
        Bkh0 = ld_bf8(kh_p); Bkh1 = ld_bf8(kh_p + 16);       // prefetch tile 2it+3
        Bkl0 = ld_bf8(kl_p); Bkl1 = ld_bf8(kl_p + 16);
        Bmw  = ml_p[(2 * it + 3) * 32];
        kh_p += 32 * D_; kl_p += 32 * D_;
        softpv(sO, mwO);
    }

    // ---- cross-wave flash merge (8 key-split partials), r7-proven ----
    __shared__ float o_lds[8][32][33];
    __shared__ float m_l[8][32];
    __shared__ float l_l[8][32];
    if (hi == 0) { m_l[w][lq] = m_run; l_l[w][lq] = l_run; }
    #pragma unroll
    for (int r = 0; r < 16; ++r) {
        const int d = (r & 3) + 8 * (r >> 2) + 4 * hi;
        o_lds[w][d][lq] = acc[r];
    }
    __syncthreads();
    {
        const int q = t >> 4;        // 0..31
        const int dp = t & 15;       // float2 over d
        float M = m_l[0][q];
        #pragma unroll
        for (int w2 = 1; w2 < 8; ++w2) M = fmaxf(M, m_l[w2][q]);
        float L = 0.f, fac[8];
        #pragma unroll
        for (int w2 = 0; w2 < 8; ++w2) {
            fac[w2] = __builtin_amdgcn_exp2f(m_l[w2][q] - M);
            L += l_l[w2][q] * fac[w2];
        }
        const float invL = 1.f / L;
        float o0 = 0.f, o1 = 0.f;
        #pragma unroll
        for (int w2 = 0; w2 < 8; ++w2) {
            o0 += o_lds[w2][dp * 2][q] * fac[w2];
            o1 += o_lds[w2][dp * 2 + 1][q] * fac[w2];
        }
        o0 = fmaxf(o0 * invL, 0.f);
        o1 = fmaxf(o1 * invL, 0.f);
        float2 ov = make_float2(o0, o1);
        *reinterpret_cast<float2*>(out + ((size_t)(b * N_ + q0 + q) * H_ + h) * D_ + dp * 2) = ov;
    }
}

extern "C" void kernel_launch(void* const* d_in, const int* in_sizes, int n_in,
                              void* d_out, int out_size, void* d_ws, size_t ws_size,
                              hipStream_t stream) {
    // inputs: vt, x, adj, fc_w, fc_b, Q1, Q2, K, V (all fp32)
    const float* x    = (const float*)d_in[1];
    const float* adj  = (const float*)d_in[2];
    const float* fc_w = (const float*)d_in[3];
    const float* fc_b = (const float*)d_in[4];
    const float* Q1   = (const float*)d_in[5];
    const float* Q2   = (const float*)d_in[6];
    const float* K    = (const float*)d_in[7];
    const float* V    = (const float*)d_in[8];
    float* out = (float*)d_out;

    char* ws = (char*)d_ws;
    const size_t MB = 1024 * 1024;
    unsigned short* QtH = (unsigned short*)(ws);             // 2 MB each
    unsigned short* QtL = (unsigned short*)(ws + 2 * MB);
    unsigned short* KtH = (unsigned short*)(ws + 4 * MB);
    unsigned short* KtL = (unsigned short*)(ws + 6 * MB);
    unsigned short* Vt  = (unsigned short*)(ws + 8 * MB);
    unsigned short* VtT = (unsigned short*)(ws + 10 * MB);
    unsigned*     maskL = (unsigned*)    (ws + 12 * MB);     // 2 MB: [12, 14) MB
    float*        fc_wT = (float*)       (ws + 14 * MB);     // 32 KB

    hipLaunchKernelGGL(prep_fcT, dim3(32), dim3(256), 0, stream, fc_w, fc_wT);
    hipLaunchKernelGGL(pack_adjL, dim3(N_ * N_ / 256), dim3(256), 0, stream, adj, maskL);
    hipLaunchKernelGGL(proj_kernel, dim3(B_ * N_ / 8), dim3(128), 0, stream,
                       x, fc_wT, fc_b, Q1, Q2, K, V, QtH, QtL, KtH, KtL, Vt);
    hipLaunchKernelGGL(vtrans, dim3(8 * (N_ / 64)), dim3(256), 0, stream, Vt, VtT);
    hipLaunchKernelGGL(flash_mfma, dim3(B_ * H_ * (N_ / 32)), dim3(512), 0, stream,
                       QtH, QtL, KtH, KtL, VtT, maskL, out);
}